// Round 2
// baseline (741.901 us; speedup 1.0000x reference)
//
#include <hip/hip_runtime.h>

#define B_      64
#define CIN     64
#define HW      3136
#define W56     56
#define COUT    128
#define CH512   512
#define IN_DIM  200704
#define SPLIT   392          // split-K blocks; 200704/392 = 512
#define KPER    512
#define CHUNKS  16           // KPER/32
#define XS_STRIDE 72         // padded cin stride (16B aligned, 2-way banks only)
#define WS_STRIDE 40         // padded k stride for [row][32k] tiles

typedef __attribute__((ext_vector_type(8))) short short8;
typedef __attribute__((ext_vector_type(4))) float floatx4;

__device__ __forceinline__ unsigned short f2bf(float f) {
  unsigned int u = __float_as_uint(f);
  u += 0x7FFFu + ((u >> 16) & 1u);
  return (unsigned short)(u >> 16);
}
__device__ __forceinline__ float bf2f(unsigned short h) {
  return __uint_as_float(((unsigned int)h) << 16);
}
// split 8 floats into hi/lo bf16 packed as uint4 each
__device__ __forceinline__ void split8(const float* fv, uint4& H, uint4& L) {
  unsigned int h[4], l[4];
#pragma unroll
  for (int i = 0; i < 4; ++i) {
    unsigned short h0 = f2bf(fv[2 * i]), h1 = f2bf(fv[2 * i + 1]);
    unsigned short l0 = f2bf(fv[2 * i] - bf2f(h0));
    unsigned short l1 = f2bf(fv[2 * i + 1] - bf2f(h1));
    h[i] = (unsigned)h0 | ((unsigned)h1 << 16);
    l[i] = (unsigned)l0 | ((unsigned)l1 << 16);
  }
  H = make_uint4(h[0], h[1], h[2], h[3]);
  L = make_uint4(l[0], l[1], l[2], l[3]);
}

// ---------------- K1: x NCHW fp32 -> NHWC bf16 (x_t[b][pos][cin]) -------------
__global__ __launch_bounds__(256) void k_transpose(const float* __restrict__ x,
                                                   unsigned short* __restrict__ xt) {
  __shared__ float tile[64 * 65];
  int bb = blockIdx.x / 49, pt = blockIdx.x % 49;
  int p0 = pt * 64, t = threadIdx.x;
  const float* src = x + ((size_t)bb * 64) * HW + p0;
#pragma unroll
  for (int i = 0; i < 16; ++i) {
    int e = i * 256 + t, ci = e >> 6, ps = e & 63;
    tile[ci * 65 + ps] = src[(size_t)ci * HW + ps];
  }
  __syncthreads();
  unsigned short* dst = xt + ((size_t)bb * HW + p0) * 64;
#pragma unroll
  for (int i = 0; i < 16; ++i) {
    int e = i * 256 + t, ps = e >> 6, ci = e & 63;
    dst[(size_t)ps * 64 + ci] = f2bf(tile[ci * 65 + ps]);
  }
}

// ---------------- K2: router split-bf16 MFMA split-K GEMM ---------------------
// grid = 2 n-tiles (256 c each) x SPLIT.  partial[s][b(64)][c(512)] fp32
__global__ __launch_bounds__(256) void k_router(const float* __restrict__ x,
                                                const float* __restrict__ rw,
                                                float* __restrict__ partial) {
  __shared__ unsigned short ah[64 * WS_STRIDE], al[64 * WS_STRIDE];
  __shared__ unsigned short wh[256 * WS_STRIDE], wl[256 * WS_STRIDE];
  int nt = blockIdx.x / SPLIT;
  int s = blockIdx.x % SPLIT;
  int kb = s * KPER;
  int t = threadIdx.x, lane = t & 63, wv = t >> 6;
  int l15 = lane & 15, quad = lane >> 4;
  floatx4 acc[4][4];
#pragma unroll
  for (int i = 0; i < 4; ++i)
#pragma unroll
    for (int j = 0; j < 4; ++j) acc[i][j] = (floatx4){0.f, 0.f, 0.f, 0.f};

  int xq = t & 3;
  for (int cc = 0; cc < CHUNKS; ++cc) {
    // stage x chunk [64 b][32 k] split hi/lo
    {
      int xb = t >> 2;
      const float4* p = (const float4*)(x + (size_t)xb * IN_DIM + kb + cc * 32 + xq * 8);
      float4 a0 = p[0], a1 = p[1];
      float fv[8] = {a0.x, a0.y, a0.z, a0.w, a1.x, a1.y, a1.z, a1.w};
      uint4 H, L;
      split8(fv, H, L);
      *(uint4*)&ah[xb * WS_STRIDE + xq * 8] = H;
      *(uint4*)&al[xb * WS_STRIDE + xq * 8] = L;
    }
    // stage w chunk [256 c][32 k] split hi/lo
#pragma unroll
    for (int i = 0; i < 4; ++i) {
      int cl = (t >> 2) + i * 64;
      const float4* p =
          (const float4*)(rw + ((size_t)(nt * 256 + cl)) * IN_DIM + kb + cc * 32 + xq * 8);
      float4 a0 = p[0], a1 = p[1];
      float fv[8] = {a0.x, a0.y, a0.z, a0.w, a1.x, a1.y, a1.z, a1.w};
      uint4 H, L;
      split8(fv, H, L);
      *(uint4*)&wh[cl * WS_STRIDE + xq * 8] = H;
      *(uint4*)&wl[cl * WS_STRIDE + xq * 8] = L;
    }
    __syncthreads();
    short8 Ah[4], Al[4];
#pragma unroll
    for (int mi = 0; mi < 4; ++mi) {
      int row = mi * 16 + l15;
      Ah[mi] = *(short8*)&ah[row * WS_STRIDE + quad * 8];
      Al[mi] = *(short8*)&al[row * WS_STRIDE + quad * 8];
    }
#pragma unroll
    for (int nj = 0; nj < 4; ++nj) {
      int c = wv * 64 + nj * 16 + l15;
      short8 Bh = *(short8*)&wh[c * WS_STRIDE + quad * 8];
      short8 Bl = *(short8*)&wl[c * WS_STRIDE + quad * 8];
#pragma unroll
      for (int mi = 0; mi < 4; ++mi) {
        acc[mi][nj] = __builtin_amdgcn_mfma_f32_16x16x32_bf16(Ah[mi], Bh, acc[mi][nj], 0, 0, 0);
        acc[mi][nj] = __builtin_amdgcn_mfma_f32_16x16x32_bf16(Al[mi], Bh, acc[mi][nj], 0, 0, 0);
        acc[mi][nj] = __builtin_amdgcn_mfma_f32_16x16x32_bf16(Ah[mi], Bl, acc[mi][nj], 0, 0, 0);
      }
    }
    __syncthreads();
  }
#pragma unroll
  for (int mi = 0; mi < 4; ++mi)
#pragma unroll
    for (int nj = 0; nj < 4; ++nj)
#pragma unroll
      for (int r = 0; r < 4; ++r) {
        int brow = mi * 16 + quad * 4 + r;
        int cg = nt * 256 + wv * 64 + nj * 16 + l15;
        partial[((size_t)s * 64 + brow) * 512 + cg] = acc[mi][nj][r];
      }
}

// ---------------- K3: reduce partials + exact top-128 select ------------------
__global__ __launch_bounds__(512) void k_topk(const float* __restrict__ partial,
                                              const float* __restrict__ rb,
                                              const float* __restrict__ cb,
                                              int* __restrict__ idx,
                                              float* __restrict__ bsel) {
  __shared__ float as_[512];
  __shared__ int keep[512];
  int b = blockIdx.x, t = threadIdx.x;
  float v = 0.f;
#pragma unroll 8
  for (int s = 0; s < SPLIT; ++s) v += partial[((size_t)s * 64 + b) * 512 + t];
  v += rb[t];
  float av = fabsf(v);
  as_[t] = av;
  __syncthreads();
  int rank = 0;
  for (int j = 0; j < 512; ++j) {
    float aj = as_[j];
    rank += (aj > av) || (aj == av && j < t);
  }
  keep[t] = (rank < 128) ? 1 : 0;
  __syncthreads();
  if (rank < 128) {
    int pos = 0;
    for (int j = 0; j < 512; ++j) pos += (j < t) ? keep[j] : 0;
    idx[b * 128 + pos] = t;
    bsel[b * 128 + pos] = cb[t];
  }
}

// ---------------- K4: gather selected conv weights to bf16, K = tap*64+cin ----
__global__ __launch_bounds__(256) void k_gather(const float* __restrict__ cw,
                                                const int* __restrict__ idx,
                                                unsigned short* __restrict__ wsel) {
  int t = threadIdx.x, lane = t & 63, wv = t >> 6;
  int id = blockIdx.x * 4 + wv;
  int b = id >> 7, j = id & 127;
  int c = idx[b * 128 + j];
  const float* src = cw + (size_t)c * 576 + lane * 9;
  unsigned short* dst = wsel + ((size_t)(b * 128 + j)) * 576 + lane;
#pragma unroll
  for (int i = 0; i < 9; ++i) dst[i * 64] = f2bf(src[i]);
}

// ---------------- K5: selective 3x3 conv via MFMA (A=w[ch], B=x im2col) -------
// block = (b, 128-pos tile); LDS x halo tile staged once; 18 K-chunks of 32.
// NOTE: 6 staged rows (r0-1..r0+4): tiles with p0%56==48 span 4 output rows,
// so dy=+1 taps on the last row need global row r0+4 (round-1 OOB bug).
__global__ __launch_bounds__(256) void k_conv(const unsigned short* __restrict__ xt,
                                              const unsigned short* __restrict__ wsel,
                                              const float* __restrict__ bsel,
                                              float* __restrict__ out) {
  __shared__ unsigned short xs[6 * 58 * XS_STRIDE];  // rows r0-1..r0+4, cols -1..56, cin(+pad)
  __shared__ unsigned short ws2[128 * WS_STRIDE];
  __shared__ float bs[128];
  int b = blockIdx.x / 25, tile = blockIdx.x % 25;
  int p0 = tile * 128;
  int r0 = p0 / 56;
  int t = threadIdx.x, lane = t & 63, wv = t >> 6;
  int l15 = lane & 15, quad = lane >> 4;
  int wy = wv >> 1, wx = wv & 1;

  const unsigned short* xb = xt + (size_t)b * HW * 64;
  for (int c = t; c < 2688; c += 256) {  // 6 rows x 56 cols x 8 x 16B
    int rr = c / 448, rem = c % 448, col = rem >> 3, part = rem & 7;
    int g = r0 - 1 + rr;
    uint4 v = make_uint4(0, 0, 0, 0);
    if (g >= 0 && g < 56) v = *(const uint4*)&xb[((size_t)g * 56 + col) * 64 + part * 8];
    *(uint4*)&xs[(rr * 58 + 1 + col) * XS_STRIDE + part * 8] = v;
  }
  if (t < 96) {  // zero the col -1 / col 56 pads (6 rows x 2 cols x 8 parts)
    int rr = t / 16, sub = t % 16, col = (sub < 8) ? 0 : 57, part = sub & 7;
    *(uint4*)&xs[(rr * 58 + col) * XS_STRIDE + part * 8] = make_uint4(0, 0, 0, 0);
  }
  if (t < 128) bs[t] = bsel[b * 128 + t];

  int pbase[4], xybase[4];
#pragma unroll
  for (int nj = 0; nj < 4; ++nj) {
    int p = p0 + wx * 64 + nj * 16 + l15;
    pbase[nj] = p;
    int pe = p > 3135 ? 3135 : p;
    int y = pe / 56, xx = pe - y * 56;
    xybase[nj] = (y - r0) * 58 + xx;
  }
  int awofs[4];
#pragma unroll
  for (int mi = 0; mi < 4; ++mi) awofs[mi] = (wy * 64 + mi * 16 + l15) * WS_STRIDE + quad * 8;

  floatx4 acc[4][4];
#pragma unroll
  for (int i = 0; i < 4; ++i)
#pragma unroll
    for (int j = 0; j < 4; ++j) acc[i][j] = (floatx4){0.f, 0.f, 0.f, 0.f};

  const unsigned short* wrow = wsel + (size_t)b * 128 * 576;
  for (int cc = 0; cc < 18; ++cc) {
    int tap = cc >> 1, cin0 = (cc & 1) * 32;
    int dy = tap / 3, dx = tap - dy * 3;
#pragma unroll
    for (int i = 0; i < 2; ++i) {  // stage w chunk [128][32]
      int id = t + i * 256;
      int j = id >> 2, part = id & 3;
      *(uint4*)&ws2[j * WS_STRIDE + part * 8] =
          *(const uint4*)&wrow[(size_t)j * 576 + cc * 32 + part * 8];
    }
    __syncthreads();
    int sofs = (dy * 58 + dx) * XS_STRIDE + cin0 + quad * 8;
    short8 Bx[4];
#pragma unroll
    for (int nj = 0; nj < 4; ++nj) Bx[nj] = *(short8*)&xs[xybase[nj] * XS_STRIDE + sofs];
#pragma unroll
    for (int mi = 0; mi < 4; ++mi) {
      short8 Aw = *(short8*)&ws2[awofs[mi]];
#pragma unroll
      for (int nj = 0; nj < 4; ++nj)
        acc[mi][nj] = __builtin_amdgcn_mfma_f32_16x16x32_bf16(Aw, Bx[nj], acc[mi][nj], 0, 0, 0);
    }
    __syncthreads();
  }
#pragma unroll
  for (int mi = 0; mi < 4; ++mi) {
    int ch0 = wy * 64 + mi * 16 + quad * 4;
#pragma unroll
    for (int r = 0; r < 4; ++r) {
      int ch = ch0 + r;
      float bias = bs[ch];
      float* op = out + ((size_t)b * 128 + ch) * HW;
#pragma unroll
      for (int nj = 0; nj < 4; ++nj) {
        int p = pbase[nj];
        if (p < HW) op[p] = acc[mi][nj][r] + bias;
      }
    }
  }
}

extern "C" void kernel_launch(void* const* d_in, const int* in_sizes, int n_in,
                              void* d_out, int out_size, void* d_ws, size_t ws_size,
                              hipStream_t stream) {
  const float* x = (const float*)d_in[0];
  const float* cw = (const float*)d_in[1];
  const float* cb = (const float*)d_in[2];
  const float* rw = (const float*)d_in[3];
  const float* rb = (const float*)d_in[4];
  float* out = (float*)d_out;
  char* ws = (char*)d_ws;
  // workspace layout (86.6 MB total)
  unsigned short* xt = (unsigned short*)(ws);              // 25,690,112 B
  float* partial = (float*)(ws + 25690112);                // 51,380,224 B
  unsigned short* wsel = (unsigned short*)(ws + 77070336); //  9,437,184 B
  int* idx = (int*)(ws + 86507520);                        //     32,768 B
  float* bsel = (float*)(ws + 86540288);                   //     32,768 B

  hipLaunchKernelGGL(k_transpose, dim3(3136), dim3(256), 0, stream, x, xt);
  hipLaunchKernelGGL(k_router, dim3(2 * SPLIT), dim3(256), 0, stream, x, rw, partial);
  hipLaunchKernelGGL(k_topk, dim3(64), dim3(512), 0, stream, partial, rb, cb, idx, bsel);
  hipLaunchKernelGGL(k_gather, dim3(2048), dim3(256), 0, stream, cw, idx, wsel);
  hipLaunchKernelGGL(k_conv, dim3(1600), dim3(256), 0, stream, xt, wsel, bsel, out);
}